// Round 13
// baseline (750.005 us; speedup 1.0000x reference)
//
#include <hip/hip_runtime.h>
#include <hip/hip_bf16.h>
#include <hip/hip_cooperative_groups.h>
#include <stdint.h>

// B=16, D=64, S=2048
// scores[b,s,t] = dot(q[b,:,s],k[b,:,t])/8 ; mask -> -1000 ; softmax over s
// (query axis) ; out[b,s,d] = sum_t attn[b,s,t] v[b,d,t].
// |score|<~6: p = mask?0:exp(score/8); l[t]=sum_s p; out = (p/l) @ V^T.
//
// Round-13: ONE cooperative kernel (prep -> colsums -> linv -> output with
// grid.sync between phases) to eliminate the measured 75us of prep+launch
// gaps (r12 REP instrumentation: p1=39, p2=55, prep+gaps=75). pass2 VALU cut
// via v_cvt_pk_bf16_f32 inline asm. Runtime fallback to the r8 3-launch
// champion if cooperative launch is rejected.

namespace cg = cooperative_groups;

namespace {
constexpr int B = 16;
constexpr int D = 64;
constexpr int S = 2048;
constexpr float SCALE = 0.125f;

typedef __attribute__((ext_vector_type(8))) short short8; // 8 bf16
typedef __attribute__((ext_vector_type(4))) float f32x4;

constexpr size_t WS_FLAG  = 0;
constexpr size_t WS_LINV  = 256;                    // B*S f32 = 128KB
constexpr size_t WS_LPART = 256 + 131072;           // 4*B*S f32 (fallback uses 4; coop uses 2)
constexpr size_t WS_QT    = 655616;                 // B*S*D bf16 = 4MB
constexpr size_t WS_KT    = 4849920;
constexpr size_t WS_VB    = 9044224;
constexpr size_t WS_MPACK = 13238528;               // B*(S/64)*S u64 = 8MB
constexpr size_t NEED_T1  = 21627136;
}

__device__ __forceinline__ bool mask_at(const void* mask, int mode, size_t idx) {
    if (mode == 1) return ((const int*)mask)[idx] != 0;
    if (mode == 2) return ((const float*)mask)[idx] != 0.0f;
    return ((const unsigned char*)mask)[idx] != 0;
}

__device__ __forceinline__ uint16_t f2bf(float f) {
    unsigned int u = __float_as_uint(f);
    unsigned int r = (u + 0x7fffu + ((u >> 16) & 1u)) >> 16;
    return (uint16_t)r;
}
// v_cvt_pk_bf16_f32: lo16 = bf16(a), hi16 = bf16(b), RNE (same as f2bf)
__device__ __forceinline__ unsigned int cvtpk(float a, float b) {
    unsigned int r;
    asm("v_cvt_pk_bf16_f32 %0, %1, %2" : "=v"(r) : "v"(a), "v"(b));
    return r;
}

// swizzled LDS byte address for 128B-row tiles
__device__ __forceinline__ int swz(int row, int colByte) {
    return row * 128 + (colByte ^ ((row & 7) << 4));
}

__device__ __forceinline__ void gll16(const void* g, void* l) {
    __builtin_amdgcn_global_load_lds(
        (const __attribute__((address_space(1))) void*)g,
        (__attribute__((address_space(3))) void*)l, 16, 0, 0);
}

// 64-row x 128B tile; LDS linear dest, source pre-swizzled (2 gll16/thread).
__device__ __forceinline__ void stage_tile(const char* srcRows, size_t rowStrideB,
                                           unsigned char* dst, int tid) {
    const int lane = tid & 63, w = tid >> 6;
    const int lrow = lane >> 3;
    const int slot = (lane & 7) ^ lrow;
    #pragma unroll
    for (int c = 0; c < 2; ++c) {
        const int row = 16 * w + 8 * c + lrow;
        gll16(srcRows + (size_t)row * rowStrideB + slot * 16,
              dst + (16 * w + 8 * c) * 128);
    }
}

// 32-row x 128B tile (1 gll16/thread).
__device__ __forceinline__ void stage_tile32(const char* srcRows, size_t rowStrideB,
                                             unsigned char* dst, int tid) {
    const int lane = tid & 63, w = tid >> 6;
    const int lrow = lane >> 3;
    const int slot = (lane & 7) ^ lrow;
    const int row = 8 * w + lrow;
    gll16(srcRows + (size_t)row * rowStrideB + slot * 16, dst + 8 * w * 128);
}

__device__ __forceinline__ f32x4 mfma16(short8 a, short8 b, f32x4 c) {
    return __builtin_amdgcn_mfma_f32_16x16x32_bf16(a, b, c, 0, 0, 0);
}

// ===========================================================================
// FUSED COOPERATIVE KERNEL — grid (64, B), 256 threads, 4 blocks/CU.
// Phase 0: prep (q/k transpose-cvt, v cvt). Phase 1: MFMA colsums + mask
// bit-pack (wave-local dtype probe). Phase 1.5: linv. Phase 2: output.
// ===========================================================================
__global__ __launch_bounds__(256, 4)
void fused_kernel(const float* __restrict__ q, const float* __restrict__ k,
                  const float* __restrict__ v, const void* __restrict__ mask,
                  uint16_t* __restrict__ qT, uint16_t* __restrict__ kT,
                  uint16_t* __restrict__ vb, unsigned long long* __restrict__ mpackT,
                  float* __restrict__ lpart, float* __restrict__ linv,
                  float* __restrict__ out)
{
    __shared__ __align__(16) unsigned char smem[25856];

    const int tid = threadIdx.x;
    const int lane = tid & 63, w = tid >> 6;
    const int l = lane & 15, hh = lane >> 4;
    const int x = blockIdx.x;     // 0..63
    const int b = blockIdx.y;     // 0..15

    cg::grid_group grid = cg::this_grid();

    // ---------------- Phase 0: prep ----------------
    {
        // v cvt: this block covers t-range [x*32, x*32+32) for all d
        {
            const int d = tid >> 2, c = tid & 3;
            const float* row = v + ((size_t)b * D + d) * S + x * 32 + c * 8;
            uint16_t*   orow = vb + ((size_t)b * D + d) * S + x * 32 + c * 8;
            float4 v0 = *(const float4*)(row);
            float4 v1 = *(const float4*)(row + 4);
            unsigned int u4[4] = {cvtpk(v0.x, v0.y), cvtpk(v0.z, v0.w),
                                  cvtpk(v1.x, v1.y), cvtpk(v1.z, v1.w)};
            *(uint4*)orow = *(const uint4*)u4;
        }
        // q/k transpose+cvt: x<32 -> qT s-block x ; x>=32 -> kT s-block x-32
        float (*ts)[65] = (float(*)[65])smem;
        const float* src = (x < 32) ? q : k;
        uint16_t*    dst = (x < 32) ? qT : kT;
        const int s0 = ((x < 32) ? x : (x - 32)) * 64;
        {
            const int d = tid >> 2, c = tid & 3;
            const float* row = src + ((size_t)b * D + d) * S + s0 + c * 16;
            #pragma unroll
            for (int i = 0; i < 4; ++i) {
                float4 v4 = *(const float4*)(row + 4 * i);
                ts[c * 16 + 4 * i + 0][d] = v4.x;
                ts[c * 16 + 4 * i + 1][d] = v4.y;
                ts[c * 16 + 4 * i + 2][d] = v4.z;
                ts[c * 16 + 4 * i + 3][d] = v4.w;
            }
        }
        __syncthreads();
        {
            const int srow = tid >> 2, p = tid & 3;
            unsigned int u8b[8];
            #pragma unroll
            for (int j = 0; j < 8; ++j)
                u8b[j] = cvtpk(ts[srow][p * 16 + 2 * j], ts[srow][p * 16 + 2 * j + 1]);
            uint16_t* drow = dst + ((size_t)b * S + s0 + srow) * 64 + p * 16;
            *(uint4*)drow       = ((const uint4*)u8b)[0];
            *((uint4*)drow + 1) = ((const uint4*)u8b)[1];
        }
    }
    __threadfence();
    grid.sync();

    // ---------------- Phase 1: colsums + mask pack ----------------
    {
        unsigned char* ksb = smem;              // 8KB
        unsigned char* qsb = smem + 8192;       // 8KB
        unsigned short (*mbits)[4] = (unsigned short(*)[4])(smem + 16384); // 512B
        float (*red)[64] = (float(*)[64])(smem + 16896);                   // 1KB

        const int t0 = (x & 31) * 64;
        const int chunk = x >> 5;               // 0..1, s-range chunk*1024
        const int sstart = chunk * 1024;

        // wave-local mask dtype probe: first 1KB of mask buffer.
        // u8: low+high byte lanes nonzero; i32: only low; f32: only high.
        // wide (4B elems) iff NOT (low && high). f32 1.0f != 0 as int.
        bool wide;
        {
            const uint4 p4 = *(const uint4*)((const unsigned char*)mask + lane * 16);
            const unsigned int lo = (p4.x & 0xFFu) | (p4.y & 0xFFu)
                                  | (p4.z & 0xFFu) | (p4.w & 0xFFu);
            const unsigned int hi = (p4.x & 0xFFFFFF00u) | (p4.y & 0xFFFFFF00u)
                                  | (p4.z & 0xFFFFFF00u) | (p4.w & 0xFFFFFF00u);
            const bool anyLo = __any(lo != 0);
            const bool anyHi = __any(hi != 0);
            wide = !(anyLo && anyHi);
        }

        const int row_m = tid >> 2, cq = tid & 3;
        const size_t mrow_base = ((size_t)b * S + row_m) * S + t0 + cq * 16;

        int4  mr4[4];
        uint4 mr1;
        auto load_mtile = [&](int sbase) {
            if (wide) {
                const int4* p = (const int4*)((const int*)mask + mrow_base + (size_t)sbase * S);
                mr4[0] = p[0]; mr4[1] = p[1]; mr4[2] = p[2]; mr4[3] = p[3];
            } else {
                mr1 = *(const uint4*)((const unsigned char*)mask + mrow_base + (size_t)sbase * S);
            }
        };
        auto pack_mtile = [&]() -> unsigned int {
            unsigned int bits = 0;
            if (wide) {
                #pragma unroll
                for (int i = 0; i < 4; ++i) {
                    bits |= (mr4[i].x ? 1u : 0u) << (4 * i + 0);
                    bits |= (mr4[i].y ? 1u : 0u) << (4 * i + 1);
                    bits |= (mr4[i].z ? 1u : 0u) << (4 * i + 2);
                    bits |= (mr4[i].w ? 1u : 0u) << (4 * i + 3);
                }
            } else {
                const unsigned int u[4] = {mr1.x, mr1.y, mr1.z, mr1.w};
                #pragma unroll
                for (int c = 0; c < 4; ++c) {
                    bits |= ((u[c] & 0x000000FFu) ? 1u : 0u) << (4 * c + 0);
                    bits |= ((u[c] & 0x0000FF00u) ? 1u : 0u) << (4 * c + 1);
                    bits |= ((u[c] & 0x00FF0000u) ? 1u : 0u) << (4 * c + 2);
                    bits |= ((u[c] & 0xFF000000u) ? 1u : 0u) << (4 * c + 3);
                }
            }
            return bits;
        };

        stage_tile((const char*)(kT + ((size_t)b * S + t0) * 64), 128, ksb, tid);
        stage_tile((const char*)(qT + ((size_t)b * S + sstart) * 64), 128, qsb, tid);
        load_mtile(sstart);

        float colacc[4] = {0.f, 0.f, 0.f, 0.f};

        for (int it = 0; it < 16; ++it) {
            const int sbase = sstart + it * 64;

            __syncthreads(); // TOP: drains qsb staging + mask regs

            const unsigned int bits = pack_mtile();
            mbits[row_m][cq] = (unsigned short)bits;

            short8 A0 = *(const short8*)&qsb[swz(16 * w + l, 0  + hh * 16)];
            short8 A1 = *(const short8*)&qsb[swz(16 * w + l, 64 + hh * 16)];

            __syncthreads(); // MID: mbits visible; qsb ds_reads complete

            if (tid < 64) {
                const unsigned long long word =
                    (unsigned long long)mbits[tid][0]
                    | ((unsigned long long)mbits[tid][1] << 16)
                    | ((unsigned long long)mbits[tid][2] << 32)
                    | ((unsigned long long)mbits[tid][3] << 48);
                mpackT[((size_t)b * 32 + (t0 >> 6)) * S + sbase + tid] = word;
            }

            if (it < 15) {
                stage_tile((const char*)(qT + ((size_t)b * S + sbase + 64) * 64), 128, qsb, tid);
                load_mtile(sbase + 64);
            }

            const int srow_l = 16 * w + 4 * hh;
            #pragma unroll
            for (int tf = 0; tf < 4; ++tf) {
                const short8 B0 = *(const short8*)&ksb[swz(tf * 16 + l, 0  + hh * 16)];
                const short8 B1 = *(const short8*)&ksb[swz(tf * 16 + l, 64 + hh * 16)];
                f32x4 c4 = {0.f, 0.f, 0.f, 0.f};
                c4 = mfma16(A0, B0, c4);
                c4 = mfma16(A1, B1, c4);
                #pragma unroll
                for (int r = 0; r < 4; ++r) {
                    if (!((mbits[srow_l + r][tf] >> l) & 1))
                        colacc[tf] += __expf(c4[r] * SCALE);
                }
            }
        }

        #pragma unroll
        for (int tf = 0; tf < 4; ++tf) {
            colacc[tf] += __shfl_xor(colacc[tf], 16);
            colacc[tf] += __shfl_xor(colacc[tf], 32);
        }
        __syncthreads();
        if (lane < 16) {
            #pragma unroll
            for (int tf = 0; tf < 4; ++tf) red[w][tf * 16 + lane] = colacc[tf];
        }
        __syncthreads();
        if (tid < 64) {
            const float s = red[0][tid] + red[1][tid] + red[2][tid] + red[3][tid];
            lpart[(size_t)chunk * (B * S) + (size_t)b * S + t0 + tid] = s;
        }
    }
    __threadfence();
    grid.sync();

    // ---------------- Phase 1.5: linv ----------------
    if (tid < 32) {
        const int t = x * 32 + tid;
        const float s = lpart[(size_t)b * S + t] + lpart[(size_t)(B * S) + b * S + t];
        linv[(size_t)b * S + t] = 1.0f / s;
    }
    __threadfence();
    grid.sync();

    // ---------------- Phase 2: output ----------------
    {
        unsigned char* qsb = smem;              // 4KB (32 rows)
        unsigned char* ksb = smem + 4096;       // 8KB
        unsigned char* vsb = smem + 12288;      // 8KB
        unsigned char* ptb = smem + 20480;      // 4KB (32 rows)
        unsigned long long (*mrow2)[32] = (unsigned long long(*)[32])(smem + 24576); // 512B
        float (*linv_s)[64] = (float(*)[64])(smem + 25088);                          // 512B

        const int s0 = x * 32;

        auto load_meta = [&](int tile, int slot) {
            if (tid < 64) {
                linv_s[slot][tid] = linv[(size_t)b * S + tile * 64 + tid];
            } else if (tid < 96) {
                mrow2[slot][tid - 64] =
                    mpackT[((size_t)b * 32 + tile) * S + s0 + (tid - 64)];
            }
        };

        stage_tile32((const char*)(qT + ((size_t)b * S + s0) * 64), 128, qsb, tid);
        stage_tile((const char*)(kT + (size_t)b * S * 64), 128, ksb, tid);
        stage_tile((const char*)(vb + (size_t)b * D * S), (size_t)S * 2, vsb, tid);
        load_meta(0, 0);
        __syncthreads();

        short8 QB[2][2];
        #pragma unroll
        for (int sf = 0; sf < 2; ++sf)
            #pragma unroll
            for (int kh = 0; kh < 2; ++kh)
                QB[sf][kh] = *(const short8*)&qsb[swz(sf * 16 + l, kh * 64 + hh * 16)];

        f32x4 oacc[2];
        oacc[0] = (f32x4){0.f, 0.f, 0.f, 0.f};
        oacc[1] = (f32x4){0.f, 0.f, 0.f, 0.f};

        const int sbd = w & 1;
        const int dh = w >> 1;

        for (int i = 0; i < 32; ++i) {
            const int cur = i & 1, nxt = cur ^ 1;

            if (i > 0)
                stage_tile((const char*)(vb + (size_t)b * D * S + i * 64),
                           (size_t)S * 2, vsb, tid);

            short8 KA0 = *(const short8*)&ksb[swz(16 * w + l, 0  + hh * 16)];
            short8 KA1 = *(const short8*)&ksb[swz(16 * w + l, 64 + hh * 16)];
            float lv[4];
            #pragma unroll
            for (int r = 0; r < 4; ++r) lv[r] = linv_s[cur][16 * w + 4 * hh + r];

            #pragma unroll
            for (int sf = 0; sf < 2; ++sf) {
                f32x4 c4 = {0.f, 0.f, 0.f, 0.f};
                c4 = mfma16(KA0, QB[sf][0], c4);
                c4 = mfma16(KA1, QB[sf][1], c4);
                const unsigned long long bits = mrow2[cur][sf * 16 + l];
                float pv[4];
                #pragma unroll
                for (int r = 0; r < 4; ++r) {
                    const int tloc = 16 * w + 4 * hh + r;
                    pv[r] = ((bits >> tloc) & 1ull) ? 0.f : __expf(c4[r] * SCALE) * lv[r];
                }
                const int row = sf * 16 + l;
                const int cb = (32 * w + 8 * hh);
                *(uint2*)&ptb[row * 128 + (cb ^ ((row & 7) << 4))] =
                    make_uint2(cvtpk(pv[0], pv[1]), cvtpk(pv[2], pv[3]));
            }
            __syncthreads();

            if (i + 1 < 32) {
                stage_tile((const char*)(kT + ((size_t)b * S + (i + 1) * 64) * 64),
                           128, ksb, tid);
                load_meta(i + 1, nxt);
            }

            short8 PA0 = *(const short8*)&ptb[swz(sbd * 16 + l, 0  + hh * 16)];
            short8 PA1 = *(const short8*)&ptb[swz(sbd * 16 + l, 64 + hh * 16)];
            #pragma unroll
            for (int df = 0; df < 2; ++df) {
                const int drow = (dh * 2 + df) * 16 + l;
                short8 VB0 = *(const short8*)&vsb[swz(drow, 0  + hh * 16)];
                short8 VB1 = *(const short8*)&vsb[swz(drow, 64 + hh * 16)];
                oacc[df] = mfma16(PA0, VB0, oacc[df]);
                oacc[df] = mfma16(PA1, VB1, oacc[df]);
            }
            __syncthreads();
        }

        #pragma unroll
        for (int df = 0; df < 2; ++df)
            #pragma unroll
            for (int r = 0; r < 4; ++r)
                out[((size_t)b * S + s0 + sbd * 16 + 4 * hh + r) * D
                    + (dh * 2 + df) * 16 + l] = oacc[df][r];
    }
}

// ===========================================================================
// r8 3-launch fallback path (used when cooperative launch is rejected)
// ===========================================================================
__device__ __forceinline__ void probe_body(const unsigned char* mask, int* flag,
                                           int tid, int* c0s, int* c123s) {
    if (tid == 0) { *c0s = 0; *c123s = 0; }
    __syncthreads();
    int c0 = 0, c123 = 0;
    for (int f = tid; f < 65536; f += 256) {
        const int nz = (mask[f] != 0) ? 1 : 0;
        if ((f & 3) == 0) c0 += nz; else c123 += nz;
    }
    atomicAdd(c0s, c0);
    atomicAdd(c123s, c123);
    __syncthreads();
    if (tid == 0) {
        int mode = 0;
        if (*c123s == 0) mode = 1;
        else if (*c0s == 0) mode = 2;
        *flag = mode;
    }
}

__global__ void probe_mask_kernel(const unsigned char* __restrict__ mask,
                                  int* __restrict__ flag)
{
    __shared__ int c0s, c123s;
    probe_body(mask, flag, threadIdx.x, &c0s, &c123s);
}

__global__ __launch_bounds__(256, 2)
void prep_kernel(const float* __restrict__ q, const float* __restrict__ k,
                 const float* __restrict__ v,
                 uint16_t* __restrict__ qT, uint16_t* __restrict__ kT,
                 uint16_t* __restrict__ vb,
                 const unsigned char* __restrict__ mask, int* __restrict__ flag)
{
    __shared__ float ts[64][65];
    const int tid = threadIdx.x;
    const int s0 = blockIdx.x * 64;
    const int b  = blockIdx.y;

    if (blockIdx.z == 2) {
        const int d = tid >> 2, c = tid & 3;
        const float* row = v + ((size_t)b * D + d) * S + s0 + c * 16;
        uint16_t*   orow = vb + ((size_t)b * D + d) * S + s0 + c * 16;
        #pragma unroll
        for (int i = 0; i < 4; ++i) {
            float4 v4 = *(const float4*)(row + 4 * i);
            unsigned int u2[2] = {cvtpk(v4.x, v4.y), cvtpk(v4.z, v4.w)};
            *(uint2*)(orow + 4 * i) = *(const uint2*)u2;
        }
        if (blockIdx.x == 0 && blockIdx.y == 0) {
            __shared__ int c0s, c123s;
            probe_body(mask, flag, tid, &c0s, &c123s);
        }
        return;
    }

    const float* src = blockIdx.z ? k : q;
    uint16_t*    dst = blockIdx.z ? kT : qT;
    {
        const int d = tid >> 2, c = tid & 3;
        const float* row = src + ((size_t)b * D + d) * S + s0 + c * 16;
        #pragma unroll
        for (int i = 0; i < 4; ++i) {
            float4 v4 = *(const float4*)(row + 4 * i);
            ts[c * 16 + 4 * i + 0][d] = v4.x;
            ts[c * 16 + 4 * i + 1][d] = v4.y;
            ts[c * 16 + 4 * i + 2][d] = v4.z;
            ts[c * 16 + 4 * i + 3][d] = v4.w;
        }
    }
    __syncthreads();
    {
        const int srow = tid >> 2, p = tid & 3;
        unsigned int u8b[8];
        #pragma unroll
        for (int j = 0; j < 8; ++j)
            u8b[j] = cvtpk(ts[srow][p * 16 + 2 * j], ts[srow][p * 16 + 2 * j + 1]);
        uint16_t* drow = dst + ((size_t)b * S + s0 + srow) * 64 + p * 16;
        *(uint4*)drow       = ((const uint4*)u8b)[0];
        *((uint4*)drow + 1) = ((const uint4*)u8b)[1];
    }
}

__global__ __launch_bounds__(256, 4)
void pass1_kernel(const uint16_t* __restrict__ qT, const uint16_t* __restrict__ kT,
                  const void* __restrict__ mask, const int* __restrict__ flagp,
                  float* __restrict__ lpart, unsigned long long* __restrict__ mpackT)
{
    __shared__ __align__(16) unsigned char ksb[64 * 128];
    __shared__ __align__(16) unsigned char qsb[64 * 128];
    __shared__ unsigned short mbits[64][4];
    __shared__ float red[4][64];

    const int tid = threadIdx.x;
    const int lane = tid & 63, w = tid >> 6;
    const int l = lane & 15, hh = lane >> 4;
    const int t0 = blockIdx.x * 64;
    const int chunk = blockIdx.y;
    const int b = blockIdx.z;
    const int mode = *flagp;

    const int row_m = tid >> 2, cq = tid & 3;
    const size_t mrow_base = ((size_t)b * S + row_m) * S + t0 + cq * 16;

    int4  mr4[4];
    uint4 mr1;
    auto load_mtile = [&](int sbase) {
        if (mode != 0) {
            const int4* p = (const int4*)((const int*)mask + mrow_base + (size_t)sbase * S);
            mr4[0] = p[0]; mr4[1] = p[1]; mr4[2] = p[2]; mr4[3] = p[3];
        } else {
            mr1 = *(const uint4*)((const unsigned char*)mask + mrow_base + (size_t)sbase * S);
        }
    };
    auto pack_mtile = [&]() -> unsigned int {
        unsigned int bits = 0;
        if (mode != 0) {
            #pragma unroll
            for (int i = 0; i < 4; ++i) {
                bits |= (mr4[i].x ? 1u : 0u) << (4 * i + 0);
                bits |= (mr4[i].y ? 1u : 0u) << (4 * i + 1);
                bits |= (mr4[i].z ? 1u : 0u) << (4 * i + 2);
                bits |= (mr4[i].w ? 1u : 0u) << (4 * i + 3);
            }
        } else {
            const unsigned int u[4] = {mr1.x, mr1.y, mr1.z, mr1.w};
            #pragma unroll
            for (int c = 0; c < 4; ++c) {
                bits |= ((u[c] & 0x000000FFu) ? 1u : 0u) << (4 * c + 0);
                bits |= ((u[c] & 0x0000FF00u) ? 1u : 0u) << (4 * c + 1);
                bits |= ((u[c] & 0x00FF0000u) ? 1u : 0u) << (4 * c + 2);
                bits |= ((u[c] & 0xFF000000u) ? 1u : 0u) << (4 * c + 3);
            }
        }
        return bits;
    };

    stage_tile((const char*)(kT + ((size_t)b * S + t0) * 64), 128, ksb, tid);
    stage_tile((const char*)(qT + ((size_t)b * S + chunk * 512) * 64), 128, qsb, tid);
    load_mtile(chunk * 512);

    float colacc[4] = {0.f, 0.f, 0.f, 0.f};

    for (int it = 0; it < 8; ++it) {
        const int sbase = chunk * 512 + it * 64;

        __syncthreads();

        const unsigned int bits = pack_mtile();
        mbits[row_m][cq] = (unsigned short)bits;

        short8 A0 = *(const short8*)&qsb[swz(16 * w + l, 0  + hh * 16)];
        short8 A1 = *(const short8*)&qsb[swz(16 * w + l, 64 + hh * 16)];

        __syncthreads();

        if (tid < 64) {
            const unsigned long long word =
                (unsigned long long)mbits[tid][0]
                | ((unsigned long long)mbits[tid][1] << 16)
                | ((unsigned long long)mbits[tid][2] << 32)
                | ((unsigned long long)mbits[tid][3] << 48);
            mpackT[((size_t)b * 32 + (t0 >> 6)) * S + sbase + tid] = word;
        }

        if (it < 7) {
            stage_tile((const char*)(qT + ((size_t)b * S + sbase + 64) * 64), 128, qsb, tid);
            load_mtile(sbase + 64);
        }

        const int srow_l = 16 * w + 4 * hh;
        #pragma unroll
        for (int tf = 0; tf < 4; ++tf) {
            const short8 B0 = *(const short8*)&ksb[swz(tf * 16 + l, 0  + hh * 16)];
            const short8 B1 = *(const short8*)&ksb[swz(tf * 16 + l, 64 + hh * 16)];
            f32x4 c4 = {0.f, 0.f, 0.f, 0.f};
            c4 = mfma16(A0, B0, c4);
            c4 = mfma16(A1, B1, c4);
            #pragma unroll
            for (int r = 0; r < 4; ++r) {
                if (!((mbits[srow_l + r][tf] >> l) & 1))
                    colacc[tf] += __expf(c4[r] * SCALE);
            }
        }
    }

    #pragma unroll
    for (int tf = 0; tf < 4; ++tf) {
        colacc[tf] += __shfl_xor(colacc[tf], 16);
        colacc[tf] += __shfl_xor(colacc[tf], 32);
    }
    __syncthreads();
    if (lane < 16) {
        #pragma unroll
        for (int tf = 0; tf < 4; ++tf) red[w][tf * 16 + lane] = colacc[tf];
    }
    __syncthreads();
    if (tid < 64) {
        const float s = red[0][tid] + red[1][tid] + red[2][tid] + red[3][tid];
        lpart[(size_t)chunk * (B * S) + (size_t)b * S + t0 + tid] = s;
    }
}

__global__ __launch_bounds__(256, 4)
void pass2_kernel(const uint16_t* __restrict__ qT, const uint16_t* __restrict__ kT,
                  const uint16_t* __restrict__ vb,
                  const unsigned long long* __restrict__ mpackT,
                  const float* __restrict__ lpart, float* __restrict__ out)
{
    __shared__ __align__(16) unsigned char qsb[32 * 128];
    __shared__ __align__(16) unsigned char ksb[64 * 128];
    __shared__ __align__(16) unsigned char vsb[64 * 128];
    __shared__ __align__(16) unsigned char ptb[32 * 128];
    __shared__ unsigned long long mrow2[2][32];
    __shared__ float linv_s[2][64];

    const int tid = threadIdx.x;
    const int lane = tid & 63, w = tid >> 6;
    const int l = lane & 15, hh = lane >> 4;
    const int s0 = blockIdx.x * 32;
    const int b = blockIdx.y;

    auto load_meta = [&](int tile, int slot) {
        if (tid < 64) {
            const int t = tile * 64 + tid;
            const float s = lpart[(size_t)b * S + t]
                          + lpart[(size_t)(B * S) + b * S + t]
                          + lpart[(size_t)(2 * B * S) + b * S + t]
                          + lpart[(size_t)(3 * B * S) + b * S + t];
            linv_s[slot][tid] = 1.0f / s;
        } else if (tid < 96) {
            mrow2[slot][tid - 64] =
                mpackT[((size_t)b * 32 + tile) * S + s0 + (tid - 64)];
        }
    };

    stage_tile32((const char*)(qT + ((size_t)b * S + s0) * 64), 128, qsb, tid);
    stage_tile((const char*)(kT + (size_t)b * S * 64), 128, ksb, tid);
    stage_tile((const char*)(vb + (size_t)b * D * S), (size_t)S * 2, vsb, tid);
    load_meta(0, 0);
    __syncthreads();

    short8 QB[2][2];
    #pragma unroll
    for (int sf = 0; sf < 2; ++sf)
        #pragma unroll
        for (int kh = 0; kh < 2; ++kh)
            QB[sf][kh] = *(const short8*)&qsb[swz(sf * 16 + l, kh * 64 + hh * 16)];

    f32x4 oacc[2];
    oacc[0] = (f32x4){0.f, 0.f, 0.f, 0.f};
    oacc[1] = (f32x4){0.f, 0.f, 0.f, 0.f};

    const int sbd = w & 1;
    const int dh = w >> 1;

    for (int i = 0; i < 32; ++i) {
        const int cur = i & 1, nxt = cur ^ 1;

        if (i > 0)
            stage_tile((const char*)(vb + (size_t)b * D * S + i * 64),
                       (size_t)S * 2, vsb, tid);

        short8 KA0 = *(const short8*)&ksb[swz(16 * w + l, 0  + hh * 16)];
        short8 KA1 = *(const short8*)&ksb[swz(16 * w + l, 64 + hh * 16)];
        float lv[4];
        #pragma unroll
        for (int r = 0; r < 4; ++r) lv[r] = linv_s[cur][16 * w + 4 * hh + r];

        #pragma unroll
        for (int sf = 0; sf < 2; ++sf) {
            f32x4 c4 = {0.f, 0.f, 0.f, 0.f};
            c4 = mfma16(KA0, QB[sf][0], c4);
            c4 = mfma16(KA1, QB[sf][1], c4);
            const unsigned long long bits = mrow2[cur][sf * 16 + l];
            float pv[4];
            #pragma unroll
            for (int r = 0; r < 4; ++r) {
                const int tloc = 16 * w + 4 * hh + r;
                pv[r] = ((bits >> tloc) & 1ull) ? 0.f : __expf(c4[r] * SCALE) * lv[r];
            }
            const int row = sf * 16 + l;
            const int cb = (32 * w + 8 * hh);
            *(uint2*)&ptb[row * 128 + (cb ^ ((row & 7) << 4))] =
                make_uint2(cvtpk(pv[0], pv[1]), cvtpk(pv[2], pv[3]));
        }
        __syncthreads();

        if (i + 1 < 32) {
            stage_tile((const char*)(kT + ((size_t)b * S + (i + 1) * 64) * 64),
                       128, ksb, tid);
            load_meta(i + 1, nxt);
        }

        short8 PA0 = *(const short8*)&ptb[swz(sbd * 16 + l, 0  + hh * 16)];
        short8 PA1 = *(const short8*)&ptb[swz(sbd * 16 + l, 64 + hh * 16)];
        #pragma unroll
        for (int df = 0; df < 2; ++df) {
            const int drow = (dh * 2 + df) * 16 + l;
            short8 VB0 = *(const short8*)&vsb[swz(drow, 0  + hh * 16)];
            short8 VB1 = *(const short8*)&vsb[swz(drow, 64 + hh * 16)];
            oacc[df] = mfma16(PA0, VB0, oacc[df]);
            oacc[df] = mfma16(PA1, VB1, oacc[df]);
        }
        __syncthreads();
    }

    #pragma unroll
    for (int df = 0; df < 2; ++df)
        #pragma unroll
        for (int r = 0; r < 4; ++r)
            out[((size_t)b * S + s0 + sbd * 16 + 4 * hh + r) * D
                + (dh * 2 + df) * 16 + l] = oacc[df][r];
}

// ===========================================================================
// fp32 fallback (tiny ws)
// ===========================================================================
__global__ __launch_bounds__(256, 2)
void colsum_fb(const float* __restrict__ q, const float* __restrict__ k,
               const void* __restrict__ mask, const int* __restrict__ flagp,
               float* __restrict__ lsums)
{
    __shared__ __align__(16) float qs[128][68];
    __shared__ __align__(16) float ks[64][68];
    __shared__ float lred[32][66];
    const int tid = threadIdx.x;
    const int b = blockIdx.y;
    const int t0 = blockIdx.x * 64;
    const int mode = *flagp;
    {
        const int tl = tid & 63, d0 = tid >> 6;
        #pragma unroll
        for (int i = 0; i < 16; ++i) { const int d = d0 + i * 4; ks[tl][d] = k[(b * D + d) * S + t0 + tl]; }
    }
    const int tq = tid & 7, sq = tid >> 3;
    float lacc[8];
    #pragma unroll
    for (int j = 0; j < 8; ++j) lacc[j] = 0.f;
    const size_t mbase = (size_t)b * S * S;
    for (int s0 = 0; s0 < S; s0 += 128) {
        __syncthreads();
        {
            const int sl = tid & 127, d0 = tid >> 7;
            #pragma unroll
            for (int i = 0; i < 32; ++i) { const int d = d0 + i * 2; qs[sl][d] = q[(b * D + d) * S + s0 + sl]; }
        }
        __syncthreads();
        float acc[4][8];
        #pragma unroll
        for (int jj = 0; jj < 4; ++jj)
            #pragma unroll
            for (int j = 0; j < 8; ++j) acc[jj][j] = 0.f;
        #pragma unroll
        for (int dblk = 0; dblk < 16; ++dblk) {
            float4 q4[4];
            #pragma unroll
            for (int jj = 0; jj < 4; ++jj) q4[jj] = *(const float4*)&qs[sq + 32 * jj][dblk * 4];
            #pragma unroll
            for (int j = 0; j < 8; ++j) {
                const float4 k4 = *(const float4*)&ks[tq + 8 * j][dblk * 4];
                #pragma unroll
                for (int jj = 0; jj < 4; ++jj)
                    acc[jj][j] += q4[jj].x * k4.x + q4[jj].y * k4.y + q4[jj].z * k4.z + q4[jj].w * k4.w;
            }
        }
        #pragma unroll
        for (int jj = 0; jj < 4; ++jj) {
            const int sg = s0 + sq + 32 * jj;
            const size_t ridx = mbase + (size_t)sg * S + t0;
            #pragma unroll
            for (int j = 0; j < 8; ++j)
                if (!mask_at(mask, mode, ridx + tq + 8 * j)) lacc[j] += __expf(acc[jj][j] * SCALE);
        }
    }
    __syncthreads();
    #pragma unroll
    for (int j = 0; j < 8; ++j) lred[sq][tq + 8 * j] = lacc[j];
    __syncthreads();
    if (tid < 64) {
        float s = 0.f;
        #pragma unroll
        for (int i = 0; i < 32; ++i) s += lred[i][tid];
        lsums[b * S + t0 + tid] = s;
    }
}

__global__ __launch_bounds__(256, 2)
void attn_out_fb(const float* __restrict__ q, const float* __restrict__ k,
                 const float* __restrict__ v, const void* __restrict__ mask,
                 const int* __restrict__ flagp, const float* __restrict__ lsums,
                 float* __restrict__ out)
{
    __shared__ __align__(16) float qs[64][68];
    __shared__ __align__(16) float kw[64][68];
    __shared__ __align__(16) float pt[64][68];
    __shared__ float linv_sh[64];
    const int tid = threadIdx.x;
    const int b = blockIdx.y;
    const int s0 = blockIdx.x * 64;
    const int mode = *flagp;
    {
        const int sl = tid & 63, d0 = tid >> 6;
        #pragma unroll
        for (int i = 0; i < 16; ++i) { const int d = d0 + i * 4; qs[sl][d] = q[(b * D + d) * S + s0 + sl]; }
    }
    const int tq = tid & 7, sq = tid >> 3;
    float oacc[2][8];
    #pragma unroll
    for (int jj = 0; jj < 2; ++jj)
        #pragma unroll
        for (int dd = 0; dd < 8; ++dd) oacc[jj][dd] = 0.f;
    const size_t mbase = (size_t)b * S * S;
    for (int t0 = 0; t0 < S; t0 += 64) {
        __syncthreads();
        if (tid < 64) linv_sh[tid] = 1.f / lsums[b * S + t0 + tid];
        {
            const int tl = tid & 63, d0 = tid >> 6;
            #pragma unroll
            for (int i = 0; i < 16; ++i) { const int d = d0 + i * 4; kw[tl][d] = k[(b * D + d) * S + t0 + tl]; }
        }
        __syncthreads();
        float sc[2][8];
        #pragma unroll
        for (int jj = 0; jj < 2; ++jj)
            #pragma unroll
            for (int j = 0; j < 8; ++j) sc[jj][j] = 0.f;
        #pragma unroll
        for (int dblk = 0; dblk < 16; ++dblk) {
            float4 q4[2];
            #pragma unroll
            for (int jj = 0; jj < 2; ++jj) q4[jj] = *(const float4*)&qs[sq + 32 * jj][dblk * 4];
            #pragma unroll
            for (int j = 0; j < 8; ++j) {
                const float4 k4 = *(const float4*)&kw[tq + 8 * j][dblk * 4];
                #pragma unroll
                for (int jj = 0; jj < 2; ++jj)
                    sc[jj][j] += q4[jj].x * k4.x + q4[jj].y * k4.y + q4[jj].z * k4.z + q4[jj].w * k4.w;
            }
        }
        #pragma unroll
        for (int jj = 0; jj < 2; ++jj) {
            const int sg = s0 + sq + 32 * jj;
            const size_t ridx = mbase + (size_t)sg * S + t0;
            #pragma unroll
            for (int j = 0; j < 8; ++j) {
                const int tl = tq + 8 * j;
                const bool msk = mask_at(mask, mode, ridx + tl);
                pt[tl][sq + 32 * jj] = msk ? 0.f : __expf(sc[jj][j] * SCALE) * linv_sh[tl];
            }
        }
        __syncthreads();
        {
            const int tl = tid & 63, d0 = tid >> 6;
            #pragma unroll
            for (int i = 0; i < 16; ++i) { const int d = d0 + i * 4; kw[tl][d] = v[(b * D + d) * S + t0 + tl]; }
        }
        __syncthreads();
        #pragma unroll 8
        for (int t = 0; t < 64; ++t) {
            const float2 p2 = *(const float2*)&pt[t][sq * 2];
            const float4 w0 = *(const float4*)&kw[t][tq * 8];
            const float4 w1 = *(const float4*)&kw[t][tq * 8 + 4];
            oacc[0][0] += p2.x * w0.x; oacc[0][1] += p2.x * w0.y; oacc[0][2] += p2.x * w0.z; oacc[0][3] += p2.x * w0.w;
            oacc[0][4] += p2.x * w1.x; oacc[0][5] += p2.x * w1.y; oacc[0][6] += p2.x * w1.z; oacc[0][7] += p2.x * w1.w;
            oacc[1][0] += p2.y * w0.x; oacc[1][1] += p2.y * w0.y; oacc[1][2] += p2.y * w0.z; oacc[1][3] += p2.y * w0.w;
            oacc[1][4] += p2.y * w1.x; oacc[1][5] += p2.y * w1.y; oacc[1][6] += p2.y * w1.z; oacc[1][7] += p2.y * w1.w;
        }
    }
    #pragma unroll
    for (int jj = 0; jj < 2; ++jj) {
        float* dst = out + ((size_t)(b * S + s0 + sq * 2 + jj)) * D + tq * 8;
        *(float4*)dst = make_float4(oacc[jj][0], oacc[jj][1], oacc[jj][2], oacc[jj][3]);
        *(float4*)(dst + 4) = make_float4(oacc[jj][4], oacc[jj][5], oacc[jj][6], oacc[jj][7]);
    }
}

extern "C" void kernel_launch(void* const* d_in, const int* in_sizes, int n_in,
                              void* d_out, int out_size, void* d_ws, size_t ws_size,
                              hipStream_t stream) {
    const float* q = (const float*)d_in[0];
    const float* k = (const float*)d_in[1];
    const float* v = (const float*)d_in[2];
    const void*  mask = d_in[3];
    float* out = (float*)d_out;
    char* ws = (char*)d_ws;

    int* flag = (int*)(ws + WS_FLAG);

    if (ws_size >= NEED_T1) {
        float*    linv  = (float*)(ws + WS_LINV);
        float*    lpart = (float*)(ws + WS_LPART);
        uint16_t* qT    = (uint16_t*)(ws + WS_QT);
        uint16_t* kT    = (uint16_t*)(ws + WS_KT);
        uint16_t* vb    = (uint16_t*)(ws + WS_VB);
        unsigned long long* mpackT = (unsigned long long*)(ws + WS_MPACK);

        // Attempt single fused cooperative launch (zero inter-kernel gaps).
        const float* qa = q; const float* ka = k; const float* va = v;
        const void* ma = mask;
        uint16_t* qTa = qT; uint16_t* kTa = kT; uint16_t* vba = vb;
        unsigned long long* mpa = mpackT;
        float* lpa = lpart; float* lia = linv; float* oa = out;
        void* args[] = { &qa, &ka, &va, &ma, &qTa, &kTa, &vba, &mpa, &lpa, &lia, &oa };
        hipError_t err = hipLaunchCooperativeKernel(
            (void*)fused_kernel, dim3(64, B), dim3(256), args, 0, stream);

        if (err != hipSuccess) {
            (void)hipGetLastError(); // clear sticky error; use 3-launch path
            prep_kernel<<<dim3(S / 64, B, 3), 256, 0, stream>>>(
                q, k, v, qT, kT, vb, (const unsigned char*)mask, flag);
            pass1_kernel<<<dim3(S / 64, 4, B), 256, 0, stream>>>(
                qT, kT, mask, flag, lpart, mpackT);
            pass2_kernel<<<dim3(S / 32, B), 256, 0, stream>>>(
                qT, kT, vb, mpackT, lpart, out);
        }
    } else {
        float* lsums = (float*)(ws + WS_LINV);
        probe_mask_kernel<<<1, 256, 0, stream>>>((const unsigned char*)mask, flag);
        dim3 grid(S / 64, B);
        colsum_fb<<<grid, 256, 0, stream>>>(q, k, mask, flag, lsums);
        attn_out_fb<<<grid, 256, 0, stream>>>(q, k, v, mask, flag, lsums, out);
    }
}

// Round 14
// 170.451 us; speedup vs baseline: 4.4001x; 4.4001x over previous
//
#include <hip/hip_runtime.h>
#include <hip/hip_bf16.h>
#include <stdint.h>

// B=16, D=64, S=2048
// scores[b,s,t] = dot(q[b,:,s],k[b,:,t])/8 ; mask -> -1000 ; softmax over s
// (query axis) ; out[b,s,d] = sum_t attn[b,s,t] v[b,d,t].
// |score|<~6: p = mask?0:exp(score/8); l[t]=sum_s p; out = (p/l) @ V^T.
//
// Round-14: revert coop fusion (refuted: 800us, XCD-coherence stalls).
// 3-launch r8 champion + two targeted fixes:
//  - prep rewritten for 1KB-contiguous q/k reads (256s x 64d tile, bf16 LDS,
//    coalesced 128B-row writeout). r12 data: prep was ~40-60us at ~1TB/s due
//    to 256B/8KB-stride reads (r4-measured-slow pattern).
//  - pass2 bf16 packing via v_cvt_pk_bf16_f32.
// pass1 untouched (mask stream measured at BW roofline, 39us).

namespace {
constexpr int B = 16;
constexpr int D = 64;
constexpr int S = 2048;
constexpr float SCALE = 0.125f;

typedef __attribute__((ext_vector_type(8))) short short8; // 8 bf16
typedef __attribute__((ext_vector_type(4))) float f32x4;

constexpr size_t WS_FLAG  = 0;
constexpr size_t WS_LINV  = 256;                    // (fallback tier)
constexpr size_t WS_LPART = 256 + 131072;           // 4*B*S f32
constexpr size_t WS_QT    = 655616;                 // B*S*D bf16 = 4MB
constexpr size_t WS_KT    = 4849920;
constexpr size_t WS_VB    = 9044224;
constexpr size_t WS_MPACK = 13238528;               // B*(S/64)*S u64 = 8MB
constexpr size_t NEED_T1  = 21627136;
}

__device__ __forceinline__ bool mask_at(const void* mask, int mode, size_t idx) {
    if (mode == 1) return ((const int*)mask)[idx] != 0;
    if (mode == 2) return ((const float*)mask)[idx] != 0.0f;
    return ((const unsigned char*)mask)[idx] != 0;
}

__device__ __forceinline__ uint16_t f2bf(float f) {
    unsigned int u = __float_as_uint(f);
    unsigned int r = (u + 0x7fffu + ((u >> 16) & 1u)) >> 16;
    return (uint16_t)r;
}
// v_cvt_pk_bf16_f32: lo16 = bf16(a), hi16 = bf16(b), RNE (matches f2bf)
__device__ __forceinline__ unsigned int cvtpk(float a, float b) {
    unsigned int r;
    asm("v_cvt_pk_bf16_f32 %0, %1, %2" : "=v"(r) : "v"(a), "v"(b));
    return r;
}

// swizzled LDS byte address for 128B-row tiles
__device__ __forceinline__ int swz(int row, int colByte) {
    return row * 128 + (colByte ^ ((row & 7) << 4));
}

__device__ __forceinline__ void gll16(const void* g, void* l) {
    __builtin_amdgcn_global_load_lds(
        (const __attribute__((address_space(1))) void*)g,
        (__attribute__((address_space(3))) void*)l, 16, 0, 0);
}

// 64-row x 128B tile; LDS linear dest, source pre-swizzled (2 gll16/thread).
__device__ __forceinline__ void stage_tile(const char* srcRows, size_t rowStrideB,
                                           unsigned char* dst, int tid) {
    const int lane = tid & 63, w = tid >> 6;
    const int lrow = lane >> 3;
    const int slot = (lane & 7) ^ lrow;
    #pragma unroll
    for (int c = 0; c < 2; ++c) {
        const int row = 16 * w + 8 * c + lrow;
        gll16(srcRows + (size_t)row * rowStrideB + slot * 16,
              dst + (16 * w + 8 * c) * 128);
    }
}

// 32-row x 128B tile (1 gll16/thread).
__device__ __forceinline__ void stage_tile32(const char* srcRows, size_t rowStrideB,
                                             unsigned char* dst, int tid) {
    const int lane = tid & 63, w = tid >> 6;
    const int lrow = lane >> 3;
    const int slot = (lane & 7) ^ lrow;
    const int row = 8 * w + lrow;
    gll16(srcRows + (size_t)row * rowStrideB + slot * 16, dst + 8 * w * 128);
}

__device__ __forceinline__ f32x4 mfma16(short8 a, short8 b, f32x4 c) {
    return __builtin_amdgcn_mfma_f32_16x16x32_bf16(a, b, c, 0, 0, 0);
}

// ---------------------------------------------------------------------------
// probe body (standalone for fallback, embedded in prep)
// ---------------------------------------------------------------------------
__device__ __forceinline__ void probe_body(const unsigned char* mask, int* flag,
                                           int tid, int* c0s, int* c123s) {
    if (tid == 0) { *c0s = 0; *c123s = 0; }
    __syncthreads();
    int c0 = 0, c123 = 0;
    for (int f = tid; f < 65536; f += 256) {
        const int nz = (mask[f] != 0) ? 1 : 0;
        if ((f & 3) == 0) c0 += nz; else c123 += nz;
    }
    atomicAdd(c0s, c0);
    atomicAdd(c123s, c123);
    __syncthreads();
    if (tid == 0) {
        int mode = 0;
        if (*c123s == 0) mode = 1;
        else if (*c0s == 0) mode = 2;
        *flag = mode;
    }
}

__global__ void probe_mask_kernel(const unsigned char* __restrict__ mask,
                                  int* __restrict__ flag)
{
    __shared__ int c0s, c123s;
    probe_body(mask, flag, threadIdx.x, &c0s, &c123s);
}

// ---------------------------------------------------------------------------
// prep (new): grid (8, B, 3).
//  z=0/1: q/k transpose+cvt, 256s x 64d tile. Reads: thread (d=tid&63,
//  cc=tid>>6) loads 256B contiguous (1KB per d-row). LDS [256][68] bf16;
//  b16 scatter-writes (2-way free); readout: thread tid emits one full
//  128B qT/kT row (coalesced).
//  z=2: v cvt, 1KB-chunk reads, coalesced writes. Block (0,0,2) probes mask.
// ---------------------------------------------------------------------------
__global__ __launch_bounds__(256, 4)
void prep_kernel(const float* __restrict__ q, const float* __restrict__ k,
                 const float* __restrict__ v,
                 uint16_t* __restrict__ qT, uint16_t* __restrict__ kT,
                 uint16_t* __restrict__ vb,
                 const unsigned char* __restrict__ mask, int* __restrict__ flag)
{
    const int tid = threadIdx.x;
    const int b = blockIdx.y;

    if (blockIdx.z == 2) {
        // ---- v cvt: block covers t-range [x*256, +256), all 64 d ----
        const int t0 = blockIdx.x * 256;
        const int tt = tid & 63, dd = tid >> 6;
        #pragma unroll 4
        for (int dl = 0; dl < 16; ++dl) {
            const int d = dl * 4 + dd;
            const float* src = v + ((size_t)b * D + d) * S + t0 + tt * 4;
            float4 v4 = *(const float4*)src;
            unsigned int u2[2] = {cvtpk(v4.x, v4.y), cvtpk(v4.z, v4.w)};
            *(uint2*)(vb + ((size_t)b * D + d) * S + t0 + tt * 4) = *(const uint2*)u2;
        }
        if (blockIdx.x == 0 && blockIdx.y == 0) {
            __shared__ int c0s, c123s;
            probe_body(mask, flag, tid, &c0s, &c123s);
        }
        return;
    }

    // ---- q/k transpose+cvt ----
    __shared__ uint16_t tsb[256 * 68]; // [s][d], 136B rows, 34.8KB
    const float* src = blockIdx.z ? k : q;
    uint16_t*    dst = blockIdx.z ? kT : qT;
    const int s0 = blockIdx.x * 256;
    const int d = tid & 63, cc = tid >> 6;

    {
        const float4* rp = (const float4*)(src + ((size_t)b * D + d) * S + s0 + cc * 64);
        #pragma unroll
        for (int j2 = 0; j2 < 16; ++j2) {
            const float4 v4 = rp[j2];
            const int sl = cc * 64 + j2 * 4;
            tsb[(sl + 0) * 68 + d] = f2bf(v4.x);
            tsb[(sl + 1) * 68 + d] = f2bf(v4.y);
            tsb[(sl + 2) * 68 + d] = f2bf(v4.z);
            tsb[(sl + 3) * 68 + d] = f2bf(v4.w);
        }
    }
    __syncthreads();
    {
        const int s = tid; // 0..255, one output row per thread
        uint2* drow = (uint2*)(dst + ((size_t)b * S + s0 + s) * 64);
        #pragma unroll
        for (int kk = 0; kk < 16; ++kk)
            drow[kk] = *(const uint2*)&tsb[s * 68 + kk * 4];
    }
}

// ---------------------------------------------------------------------------
// pass1 (r8 structure): MFMA colsums + inline streaming mask pack.
// grid (S/64, 4, B).
// ---------------------------------------------------------------------------
__global__ __launch_bounds__(256, 4)
void pass1_kernel(const uint16_t* __restrict__ qT, const uint16_t* __restrict__ kT,
                  const void* __restrict__ mask, const int* __restrict__ flagp,
                  float* __restrict__ lpart, unsigned long long* __restrict__ mpackT)
{
    __shared__ __align__(16) unsigned char ksb[64 * 128];
    __shared__ __align__(16) unsigned char qsb[64 * 128];
    __shared__ unsigned short mbits[64][4];
    __shared__ float red[4][64];

    const int tid = threadIdx.x;
    const int lane = tid & 63, w = tid >> 6;
    const int l = lane & 15, hh = lane >> 4;
    const int t0 = blockIdx.x * 64;
    const int chunk = blockIdx.y;
    const int b = blockIdx.z;
    const int mode = *flagp;

    const int row_m = tid >> 2, cq = tid & 3;
    const size_t mrow_base = ((size_t)b * S + row_m) * S + t0 + cq * 16;

    int4  mr4[4];
    uint4 mr1;
    auto load_mtile = [&](int sbase) {
        if (mode != 0) {
            const int4* p = (const int4*)((const int*)mask + mrow_base + (size_t)sbase * S);
            mr4[0] = p[0]; mr4[1] = p[1]; mr4[2] = p[2]; mr4[3] = p[3];
        } else {
            mr1 = *(const uint4*)((const unsigned char*)mask + mrow_base + (size_t)sbase * S);
        }
    };
    auto pack_mtile = [&]() -> unsigned int {
        unsigned int bits = 0;
        if (mode != 0) {
            #pragma unroll
            for (int i = 0; i < 4; ++i) {
                bits |= (mr4[i].x ? 1u : 0u) << (4 * i + 0);
                bits |= (mr4[i].y ? 1u : 0u) << (4 * i + 1);
                bits |= (mr4[i].z ? 1u : 0u) << (4 * i + 2);
                bits |= (mr4[i].w ? 1u : 0u) << (4 * i + 3);
            }
        } else {
            const unsigned int u[4] = {mr1.x, mr1.y, mr1.z, mr1.w};
            #pragma unroll
            for (int c = 0; c < 4; ++c) {
                bits |= ((u[c] & 0x000000FFu) ? 1u : 0u) << (4 * c + 0);
                bits |= ((u[c] & 0x0000FF00u) ? 1u : 0u) << (4 * c + 1);
                bits |= ((u[c] & 0x00FF0000u) ? 1u : 0u) << (4 * c + 2);
                bits |= ((u[c] & 0xFF000000u) ? 1u : 0u) << (4 * c + 3);
            }
        }
        return bits;
    };

    stage_tile((const char*)(kT + ((size_t)b * S + t0) * 64), 128, ksb, tid);
    stage_tile((const char*)(qT + ((size_t)b * S + chunk * 512) * 64), 128, qsb, tid);
    load_mtile(chunk * 512);

    float colacc[4] = {0.f, 0.f, 0.f, 0.f};

    for (int it = 0; it < 8; ++it) {
        const int sbase = chunk * 512 + it * 64;

        __syncthreads(); // TOP

        const unsigned int bits = pack_mtile();
        mbits[row_m][cq] = (unsigned short)bits;

        short8 A0 = *(const short8*)&qsb[swz(16 * w + l, 0  + hh * 16)];
        short8 A1 = *(const short8*)&qsb[swz(16 * w + l, 64 + hh * 16)];

        __syncthreads(); // MID

        if (tid < 64) {
            const unsigned long long word =
                (unsigned long long)mbits[tid][0]
                | ((unsigned long long)mbits[tid][1] << 16)
                | ((unsigned long long)mbits[tid][2] << 32)
                | ((unsigned long long)mbits[tid][3] << 48);
            mpackT[((size_t)b * 32 + (t0 >> 6)) * S + sbase + tid] = word;
        }

        if (it < 7) {
            stage_tile((const char*)(qT + ((size_t)b * S + sbase + 64) * 64), 128, qsb, tid);
            load_mtile(sbase + 64);
        }

        const int srow_l = 16 * w + 4 * hh;
        #pragma unroll
        for (int tf = 0; tf < 4; ++tf) {
            const short8 B0 = *(const short8*)&ksb[swz(tf * 16 + l, 0  + hh * 16)];
            const short8 B1 = *(const short8*)&ksb[swz(tf * 16 + l, 64 + hh * 16)];
            f32x4 c4 = {0.f, 0.f, 0.f, 0.f};
            c4 = mfma16(A0, B0, c4);
            c4 = mfma16(A1, B1, c4);
            #pragma unroll
            for (int r = 0; r < 4; ++r) {
                if (!((mbits[srow_l + r][tf] >> l) & 1))
                    colacc[tf] += __expf(c4[r] * SCALE);
            }
        }
    }

    #pragma unroll
    for (int tf = 0; tf < 4; ++tf) {
        colacc[tf] += __shfl_xor(colacc[tf], 16);
        colacc[tf] += __shfl_xor(colacc[tf], 32);
    }
    __syncthreads();
    if (lane < 16) {
        #pragma unroll
        for (int tf = 0; tf < 4; ++tf) red[w][tf * 16 + lane] = colacc[tf];
    }
    __syncthreads();
    if (tid < 64) {
        const float s = red[0][tid] + red[1][tid] + red[2][tid] + red[3][tid];
        lpart[(size_t)chunk * (B * S) + (size_t)b * S + t0 + tid] = s;
    }
}

// ---------------------------------------------------------------------------
// pass2 (r8 + cvtpk): grid (S/32, B), 4 waves, 32 s-rows per block, all t.
// Staggered single-buffer K/V prefetch; inline linv; direct out.
// ---------------------------------------------------------------------------
__global__ __launch_bounds__(256, 4)
void pass2_kernel(const uint16_t* __restrict__ qT, const uint16_t* __restrict__ kT,
                  const uint16_t* __restrict__ vb,
                  const unsigned long long* __restrict__ mpackT,
                  const float* __restrict__ lpart, float* __restrict__ out)
{
    __shared__ __align__(16) unsigned char qsb[32 * 128];
    __shared__ __align__(16) unsigned char ksb[64 * 128];
    __shared__ __align__(16) unsigned char vsb[64 * 128];
    __shared__ __align__(16) unsigned char ptb[32 * 128];
    __shared__ unsigned long long mrow2[2][32];
    __shared__ float linv_s[2][64];

    const int tid = threadIdx.x;
    const int lane = tid & 63, w = tid >> 6;
    const int l = lane & 15, hh = lane >> 4;
    const int s0 = blockIdx.x * 32;
    const int b = blockIdx.y;

    auto load_meta = [&](int tile, int slot) {
        if (tid < 64) {
            const int t = tile * 64 + tid;
            const float s = lpart[(size_t)b * S + t]
                          + lpart[(size_t)(B * S) + b * S + t]
                          + lpart[(size_t)(2 * B * S) + b * S + t]
                          + lpart[(size_t)(3 * B * S) + b * S + t];
            linv_s[slot][tid] = 1.0f / s;
        } else if (tid < 96) {
            mrow2[slot][tid - 64] =
                mpackT[((size_t)b * 32 + tile) * S + s0 + (tid - 64)];
        }
    };

    stage_tile32((const char*)(qT + ((size_t)b * S + s0) * 64), 128, qsb, tid);
    stage_tile((const char*)(kT + (size_t)b * S * 64), 128, ksb, tid);
    stage_tile((const char*)(vb + (size_t)b * D * S), (size_t)S * 2, vsb, tid);
    load_meta(0, 0);
    __syncthreads();

    short8 QB[2][2];
    #pragma unroll
    for (int sf = 0; sf < 2; ++sf)
        #pragma unroll
        for (int kh = 0; kh < 2; ++kh)
            QB[sf][kh] = *(const short8*)&qsb[swz(sf * 16 + l, kh * 64 + hh * 16)];

    f32x4 oacc[2];
    oacc[0] = (f32x4){0.f, 0.f, 0.f, 0.f};
    oacc[1] = (f32x4){0.f, 0.f, 0.f, 0.f};

    const int sbd = w & 1;
    const int dh = w >> 1;

    for (int i = 0; i < 32; ++i) {
        const int cur = i & 1, nxt = cur ^ 1;

        if (i > 0)
            stage_tile((const char*)(vb + (size_t)b * D * S + i * 64),
                       (size_t)S * 2, vsb, tid);

        short8 KA0 = *(const short8*)&ksb[swz(16 * w + l, 0  + hh * 16)];
        short8 KA1 = *(const short8*)&ksb[swz(16 * w + l, 64 + hh * 16)];
        float lv[4];
        #pragma unroll
        for (int r = 0; r < 4; ++r) lv[r] = linv_s[cur][16 * w + 4 * hh + r];

        #pragma unroll
        for (int sf = 0; sf < 2; ++sf) {
            f32x4 c4 = {0.f, 0.f, 0.f, 0.f};
            c4 = mfma16(KA0, QB[sf][0], c4);
            c4 = mfma16(KA1, QB[sf][1], c4);
            const unsigned long long bits = mrow2[cur][sf * 16 + l];
            float pv[4];
            #pragma unroll
            for (int r = 0; r < 4; ++r) {
                const int tloc = 16 * w + 4 * hh + r;
                pv[r] = ((bits >> tloc) & 1ull) ? 0.f : __expf(c4[r] * SCALE) * lv[r];
            }
            const int row = sf * 16 + l;
            const int cb = (32 * w + 8 * hh);
            *(uint2*)&ptb[row * 128 + (cb ^ ((row & 7) << 4))] =
                make_uint2(cvtpk(pv[0], pv[1]), cvtpk(pv[2], pv[3]));
        }
        __syncthreads();

        if (i + 1 < 32) {
            stage_tile((const char*)(kT + ((size_t)b * S + (i + 1) * 64) * 64),
                       128, ksb, tid);
            load_meta(i + 1, nxt);
        }

        short8 PA0 = *(const short8*)&ptb[swz(sbd * 16 + l, 0  + hh * 16)];
        short8 PA1 = *(const short8*)&ptb[swz(sbd * 16 + l, 64 + hh * 16)];
        #pragma unroll
        for (int df = 0; df < 2; ++df) {
            const int drow = (dh * 2 + df) * 16 + l;
            short8 VB0 = *(const short8*)&vsb[swz(drow, 0  + hh * 16)];
            short8 VB1 = *(const short8*)&vsb[swz(drow, 64 + hh * 16)];
            oacc[df] = mfma16(PA0, VB0, oacc[df]);
            oacc[df] = mfma16(PA1, VB1, oacc[df]);
        }
        __syncthreads();
    }

    #pragma unroll
    for (int df = 0; df < 2; ++df)
        #pragma unroll
        for (int r = 0; r < 4; ++r)
            out[((size_t)b * S + s0 + sbd * 16 + 4 * hh + r) * D
                + (dh * 2 + df) * 16 + l] = oacc[df][r];
}

// ===========================================================================
// fp32 fallback (tiny ws)
// ===========================================================================
__global__ __launch_bounds__(256, 2)
void colsum_fb(const float* __restrict__ q, const float* __restrict__ k,
               const void* __restrict__ mask, const int* __restrict__ flagp,
               float* __restrict__ lsums)
{
    __shared__ __align__(16) float qs[128][68];
    __shared__ __align__(16) float ks[64][68];
    __shared__ float lred[32][66];
    const int tid = threadIdx.x;
    const int b = blockIdx.y;
    const int t0 = blockIdx.x * 64;
    const int mode = *flagp;
    {
        const int tl = tid & 63, d0 = tid >> 6;
        #pragma unroll
        for (int i = 0; i < 16; ++i) { const int d = d0 + i * 4; ks[tl][d] = k[(b * D + d) * S + t0 + tl]; }
    }
    const int tq = tid & 7, sq = tid >> 3;
    float lacc[8];
    #pragma unroll
    for (int j = 0; j < 8; ++j) lacc[j] = 0.f;
    const size_t mbase = (size_t)b * S * S;
    for (int s0 = 0; s0 < S; s0 += 128) {
        __syncthreads();
        {
            const int sl = tid & 127, d0 = tid >> 7;
            #pragma unroll
            for (int i = 0; i < 32; ++i) { const int d = d0 + i * 2; qs[sl][d] = q[(b * D + d) * S + s0 + sl]; }
        }
        __syncthreads();
        float acc[4][8];
        #pragma unroll
        for (int jj = 0; jj < 4; ++jj)
            #pragma unroll
            for (int j = 0; j < 8; ++j) acc[jj][j] = 0.f;
        #pragma unroll
        for (int dblk = 0; dblk < 16; ++dblk) {
            float4 q4[4];
            #pragma unroll
            for (int jj = 0; jj < 4; ++jj) q4[jj] = *(const float4*)&qs[sq + 32 * jj][dblk * 4];
            #pragma unroll
            for (int j = 0; j < 8; ++j) {
                const float4 k4 = *(const float4*)&ks[tq + 8 * j][dblk * 4];
                #pragma unroll
                for (int jj = 0; jj < 4; ++jj)
                    acc[jj][j] += q4[jj].x * k4.x + q4[jj].y * k4.y + q4[jj].z * k4.z + q4[jj].w * k4.w;
            }
        }
        #pragma unroll
        for (int jj = 0; jj < 4; ++jj) {
            const int sg = s0 + sq + 32 * jj;
            const size_t ridx = mbase + (size_t)sg * S + t0;
            #pragma unroll
            for (int j = 0; j < 8; ++j)
                if (!mask_at(mask, mode, ridx + tq + 8 * j)) lacc[j] += __expf(acc[jj][j] * SCALE);
        }
    }
    __syncthreads();
    #pragma unroll
    for (int j = 0; j < 8; ++j) lred[sq][tq + 8 * j] = lacc[j];
    __syncthreads();
    if (tid < 64) {
        float s = 0.f;
        #pragma unroll
        for (int i = 0; i < 32; ++i) s += lred[i][tid];
        lsums[b * S + t0 + tid] = s;
    }
}

__global__ __launch_bounds__(256, 2)
void attn_out_fb(const float* __restrict__ q, const float* __restrict__ k,
                 const float* __restrict__ v, const void* __restrict__ mask,
                 const int* __restrict__ flagp, const float* __restrict__ lsums,
                 float* __restrict__ out)
{
    __shared__ __align__(16) float qs[64][68];
    __shared__ __align__(16) float kw[64][68];
    __shared__ __align__(16) float pt[64][68];
    __shared__ float linv_sh[64];
    const int tid = threadIdx.x;
    const int b = blockIdx.y;
    const int s0 = blockIdx.x * 64;
    const int mode = *flagp;
    {
        const int sl = tid & 63, d0 = tid >> 6;
        #pragma unroll
        for (int i = 0; i < 16; ++i) { const int d = d0 + i * 4; qs[sl][d] = q[(b * D + d) * S + s0 + sl]; }
    }
    const int tq = tid & 7, sq = tid >> 3;
    float oacc[2][8];
    #pragma unroll
    for (int jj = 0; jj < 2; ++jj)
        #pragma unroll
        for (int dd = 0; dd < 8; ++dd) oacc[jj][dd] = 0.f;
    const size_t mbase = (size_t)b * S * S;
    for (int t0 = 0; t0 < S; t0 += 64) {
        __syncthreads();
        if (tid < 64) linv_sh[tid] = 1.f / lsums[b * S + t0 + tid];
        {
            const int tl = tid & 63, d0 = tid >> 6;
            #pragma unroll
            for (int i = 0; i < 16; ++i) { const int d = d0 + i * 4; kw[tl][d] = k[(b * D + d) * S + t0 + tl]; }
        }
        __syncthreads();
        float sc[2][8];
        #pragma unroll
        for (int jj = 0; jj < 2; ++jj)
            #pragma unroll
            for (int j = 0; j < 8; ++j) sc[jj][j] = 0.f;
        #pragma unroll
        for (int dblk = 0; dblk < 16; ++dblk) {
            float4 q4[2];
            #pragma unroll
            for (int jj = 0; jj < 2; ++jj) q4[jj] = *(const float4*)&qs[sq + 32 * jj][dblk * 4];
            #pragma unroll
            for (int j = 0; j < 8; ++j) {
                const float4 k4 = *(const float4*)&kw[tq + 8 * j][dblk * 4];
                #pragma unroll
                for (int jj = 0; jj < 2; ++jj)
                    sc[jj][j] += q4[jj].x * k4.x + q4[jj].y * k4.y + q4[jj].z * k4.z + q4[jj].w * k4.w;
            }
        }
        #pragma unroll
        for (int jj = 0; jj < 2; ++jj) {
            const int sg = s0 + sq + 32 * jj;
            const size_t ridx = mbase + (size_t)sg * S + t0;
            #pragma unroll
            for (int j = 0; j < 8; ++j) {
                const int tl = tq + 8 * j;
                const bool msk = mask_at(mask, mode, ridx + tl);
                pt[tl][sq + 32 * jj] = msk ? 0.f : __expf(sc[jj][j] * SCALE) * linv_sh[tl];
            }
        }
        __syncthreads();
        {
            const int tl = tid & 63, d0 = tid >> 6;
            #pragma unroll
            for (int i = 0; i < 16; ++i) { const int d = d0 + i * 4; kw[tl][d] = v[(b * D + d) * S + t0 + tl]; }
        }
        __syncthreads();
        #pragma unroll 8
        for (int t = 0; t < 64; ++t) {
            const float2 p2 = *(const float2*)&pt[t][sq * 2];
            const float4 w0 = *(const float4*)&kw[t][tq * 8];
            const float4 w1 = *(const float4*)&kw[t][tq * 8 + 4];
            oacc[0][0] += p2.x * w0.x; oacc[0][1] += p2.x * w0.y; oacc[0][2] += p2.x * w0.z; oacc[0][3] += p2.x * w0.w;
            oacc[0][4] += p2.x * w1.x; oacc[0][5] += p2.x * w1.y; oacc[0][6] += p2.x * w1.z; oacc[0][7] += p2.x * w1.w;
            oacc[1][0] += p2.y * w0.x; oacc[1][1] += p2.y * w0.y; oacc[1][2] += p2.y * w0.z; oacc[1][3] += p2.y * w0.w;
            oacc[1][4] += p2.y * w1.x; oacc[1][5] += p2.y * w1.y; oacc[1][6] += p2.y * w1.z; oacc[1][7] += p2.y * w1.w;
        }
    }
    #pragma unroll
    for (int jj = 0; jj < 2; ++jj) {
        float* dst = out + ((size_t)(b * S + s0 + sq * 2 + jj)) * D + tq * 8;
        *(float4*)dst = make_float4(oacc[jj][0], oacc[jj][1], oacc[jj][2], oacc[jj][3]);
        *(float4*)(dst + 4) = make_float4(oacc[jj][4], oacc[jj][5], oacc[jj][6], oacc[jj][7]);
    }
}

extern "C" void kernel_launch(void* const* d_in, const int* in_sizes, int n_in,
                              void* d_out, int out_size, void* d_ws, size_t ws_size,
                              hipStream_t stream) {
    const float* q = (const float*)d_in[0];
    const float* k = (const float*)d_in[1];
    const float* v = (const float*)d_in[2];
    const void*  mask = d_in[3];
    float* out = (float*)d_out;
    char* ws = (char*)d_ws;

    int* flag = (int*)(ws + WS_FLAG);

    if (ws_size >= NEED_T1) {
        float*    lpart = (float*)(ws + WS_LPART);
        uint16_t* qT    = (uint16_t*)(ws + WS_QT);
        uint16_t* kT    = (uint16_t*)(ws + WS_KT);
        uint16_t* vb    = (uint16_t*)(ws + WS_VB);
        unsigned long long* mpackT = (unsigned long long*)(ws + WS_MPACK);

        prep_kernel<<<dim3(8, B, 3), 256, 0, stream>>>(
            q, k, v, qT, kT, vb, (const unsigned char*)mask, flag);
        pass1_kernel<<<dim3(S / 64, 4, B), 256, 0, stream>>>(
            qT, kT, mask, flag, lpart, mpackT);
        pass2_kernel<<<dim3(S / 32, B), 256, 0, stream>>>(
            qT, kT, vb, mpackT, lpart, out);
    } else {
        float* lsums = (float*)(ws + WS_LINV);
        probe_mask_kernel<<<1, 256, 0, stream>>>((const unsigned char*)mask, flag);
        dim3 grid(S / 64, B);
        colsum_fb<<<grid, 256, 0, stream>>>(q, k, mask, flag, lsums);
        attn_out_fb<<<grid, 256, 0, stream>>>(q, k, v, mask, flag, lsums, out);
    }
}